// Round 8
// baseline (6100.494 us; speedup 1.0000x reference)
//
#include <hip/hip_runtime.h>
#include <hip/hip_bf16.h>

#define T_DIM 256
#define B_DIM 128
#define F_DIM 1024
#define G_DIM 4096
#define NWGS  256

typedef short bf8   __attribute__((ext_vector_type(8)));
typedef float f32x4 __attribute__((ext_vector_type(4)));
typedef unsigned int u32x4 __attribute__((ext_vector_type(4)));
typedef unsigned long long u64;

// ---- ws layout (bytes) ----
#define OFF_CTRL  0ull          // 64 KB: flags[256]@wg*128, grpDone[16]@32768+g*128, epoch[16]@34816+r*128
#define OFF_WIP   65536ull
#define SZ_WPACK  (8ull*1024*1024)
#define OFF_WHP   (OFF_WIP + SZ_WPACK)
#define OFF_RING  (OFF_WHP + SZ_WPACK)
#define SZ_SLOT   (262144ull)                 // 128*1024 bf16
#define SZ_RING   (256ull * SZ_SLOT)          // 64 MB, write-once per dispatch
#define WS_NEED   (OFF_RING + SZ_RING)

__device__ __forceinline__ unsigned short f2bf(float v) {
  union { float f; unsigned int u; } c; c.f = v;
  unsigned int u = c.u;
  return (unsigned short)((u + 0x7fffu + ((u >> 16) & 1u)) >> 16);  // RNE
}
__device__ __forceinline__ float sigm(float x)  { return 1.f / (1.f + __expf(-x)); }
__device__ __forceinline__ float tanh_(float x) { return 1.f - 2.f / (1.f + __expf(2.f * x)); }
__device__ __forceinline__ bf8 as_bf8(u32x4 v) { union { u32x4 a; bf8 b; } u; u.a = v; return u.b; }
__device__ __forceinline__ unsigned int ld_sc1(const unsigned int* p) {
  return __hip_atomic_load(p, __ATOMIC_RELAXED, __HIP_MEMORY_SCOPE_AGENT);
}
__device__ __forceinline__ void st_sc1(unsigned int* p, unsigned int v) {
  __hip_atomic_store(p, v, __ATOMIC_RELAXED, __HIP_MEMORY_SCOPE_AGENT);
}

// ---- pack W (fp32 F x 4F) -> MFMA-B frag order bf16: (nt*32+kt)*64+lane ----
__global__ __launch_bounds__(256) void pack_w(const float* __restrict__ Wi,
                                              const float* __restrict__ Wh,
                                              unsigned short* __restrict__ wip,
                                              unsigned short* __restrict__ whp) {
  int gid = blockIdx.x * 256 + threadIdx.x;
  const float* src = (gid >= 524288) ? Wh : Wi;
  unsigned short* dst = (gid >= 524288) ? whp : wip;
  int r  = gid & 524287;
  int nt = r >> 11;
  int kt = (r >> 6) & 31;
  int l  = r & 63;
  int col = nt * 16 + (l & 15);
  int k0  = kt * 32 + ((l >> 4) << 3);
  bf8 v8;
#pragma unroll
  for (int j = 0; j < 8; ++j)
    v8[j] = (short)f2bf(src[(size_t)(k0 + j) * G_DIM + col]);
  *reinterpret_cast<bf8*>(dst + (size_t)r * 8) = v8;
}

// ---- h0 fp32 -> bf16 row-major into ring slot 0 ----
__global__ __launch_bounds__(256) void pack_h(const float* __restrict__ h0,
                                              unsigned short* __restrict__ ring) {
  int i = blockIdx.x * 256 + threadIdx.x;     // 131072
  ring[i] = f2bf(h0[i]);
}

struct SmT {
  u32x4 hst[64][64];               // 64 KB  h A-frags [mt*32+kt][lane]
  u32x4 xst[64][64];               // 64 KB  x A-frags
  float gates[4][2][16][18];       // 9.2 KB
};

__device__ __forceinline__ void stage_slot(SmT* sm, const float* __restrict__ xt,
                                           int s, int lane, int srow0, int srow1, int fcol0) {
  int kt = s & 31;
  int grow = (s >> 5) ? srow1 : srow0;
  const float4* src = reinterpret_cast<const float4*>(xt + (size_t)grow * F_DIM + kt * 32 + fcol0);
  float4 v0 = src[0], v1 = src[1];
  union { __hip_bfloat162 h2[4]; u32x4 q; } cv;
  cv.h2[0] = __float22bfloat162_rn(make_float2(v0.x, v0.y));
  cv.h2[1] = __float22bfloat162_rn(make_float2(v0.z, v0.w));
  cv.h2[2] = __float22bfloat162_rn(make_float2(v1.x, v1.y));
  cv.h2[3] = __float22bfloat162_rn(make_float2(v1.z, v1.w));
  sm->xst[s][lane] = cv.q;
}

// ---- persistent scan: 256 WGs x 256 thr; wave = gate; Wh in regs ----
__global__ __launch_bounds__(256, 1) void lstm_scan(
    const float* __restrict__ x,                // (T,B,F) fp32
    const unsigned short* __restrict__ wip,
    const unsigned short* __restrict__ whp,
    unsigned short* __restrict__ ring,          // 256 slots, row-major bf16
    const float* __restrict__ bias,
    const int*   __restrict__ term,
    const float* __restrict__ c0,
    float* __restrict__ out,
    unsigned int* __restrict__ ctrl) {

  __shared__ SmT sm;

  unsigned int* flagsA = ctrl;                  // flag[wg]    @ dword wg*32
  unsigned int* grpD   = ctrl + 8192;           // grpDone[g]  @ byte 32768 + g*128
  unsigned int* epochR = ctrl + 8704;           // epoch[r]    @ byte 34816 + r*128

  const int wg    = blockIdx.x;
  const int fg    = wg & 63;
  const int mpair = wg >> 6;                    // 0..3 -> rows mpair*32..+32
  const int tid   = threadIdx.x;
  const int wv    = tid >> 6;                   // gate 0..3 (i,f,g,o)
  const int lane  = tid & 63;
  const int col   = lane & 15;
  const int oct   = lane >> 4;                  // k-octet 0..3
  const int fi    = fg * 16 + col;

  // resident Wh fragments for ntile wv*64+fg (128 VGPRs)
  bf8 wh[32];
  {
    const bf8* whb = reinterpret_cast<const bf8*>(whp) + (size_t)(wv * 64 + fg) * 2048 + lane;
#pragma unroll
    for (int kt = 0; kt < 32; ++kt) wh[kt] = whb[kt * 64];
  }
  const bf8* wib = reinterpret_cast<const bf8*>(wip) + (size_t)(wv * 64 + fg) * 2048 + lane;

  float b4[4];
#pragma unroll
  for (int g = 0; g < 4; ++g) b4[g] = bias[g * F_DIM + fi];

  float c_reg[2];
  {
    int wr0 = wv * 8 + oct;
    c_reg[0] = c0[(size_t)(mpair * 32 + wr0)     * F_DIM + fi];
    c_reg[1] = c0[(size_t)(mpair * 32 + wr0 + 4) * F_DIM + fi];
  }

  const int srow0 = mpair * 32 + col;            // staged batch row, mt=0
  const int srow1 = srow0 + 16;                  // mt=1
  const int fcol0 = oct * 8;

  float* fc = out + (size_t)T_DIM * B_DIM * F_DIM;
  float* fh = fc + (size_t)B_DIM * F_DIM;

  // ---- prologue: all waves stage x(0) ----
#pragma unroll 4
  for (int i = 0; i < 16; ++i)
    stage_slot(&sm, x, wv + 4 * i, lane, srow0, srow1, fcol0);

#pragma unroll 1
  for (int t = 0; t < T_DIM; ++t) {
    // ---- B. tree barrier wait (wave 0 only; others arrive staged) ----
    if (t > 0 && wv == 0) {
      const unsigned int tgt = (unsigned int)t;
      if (wg < 16) {
        // leader: poll 16 children flags (distinct lines, one load/lane)
        const unsigned int* cf = flagsA + (((wg << 4) | (lane & 15)) << 5);
        for (;;) { unsigned int f = ld_sc1(cf); if (__all(f >= tgt)) break; }
        if (wg == 0) {
          if (lane == 0) st_sc1(grpD, tgt);
          const unsigned int* gd = grpD + ((lane & 15) << 5);
          for (;;) { unsigned int f = ld_sc1(gd); if (__all(f >= tgt)) break; }
          if (lane < 16) st_sc1(epochR + (lane << 5), tgt);
        } else {
          if (lane == 0) st_sc1(grpD + (wg << 5), tgt);
          const unsigned int* ep = epochR + ((wg & 15) << 5);
          unsigned int e;
          do {
            e = (lane == 0) ? ld_sc1(ep) : 0u;
            e = (unsigned int)__shfl((int)e, 0, 64);
          } while (e < tgt);
        }
      } else {
        const unsigned int* ep = epochR + ((wg & 15) << 5);
        unsigned int e;
        do {
          e = (lane == 0) ? ld_sc1(ep) : 0u;
          e = (unsigned int)__shfl((int)e, 0, 64);
        } while (e < tgt);
      }
      asm volatile("" ::: "memory");
    }
    __syncthreads();   // epoch detected + xst(t) staged

    const int trm0 = term[t * B_DIM + srow0];
    const int trm1 = term[t * B_DIM + srow1];
    const unsigned short* hslot = ring + (size_t)t * 131072;

    // ---- C1. issue first 8 h loads (plain cached, coalesced 16B) ----
    u32x4 hq[8];
#pragma unroll
    for (int i = 0; i < 8; ++i) {
      int g2 = wv + 4 * i;
      int kt = g2 & 31;
      int grow = (g2 >> 5) ? srow1 : srow0;
      hq[i] = *reinterpret_cast<const u32x4*>(hslot + (size_t)grow * F_DIM + kt * 32 + fcol0);
    }

    // ---- C2. x @ Wi first half (hides h latency) ----
    f32x4 a0 = {0, 0, 0, 0}, a1 = {0, 0, 0, 0};
#pragma unroll
    for (int kt = 0; kt < 16; ++kt) {
      bf8 wiF = wib[kt * 64];
      a0 = __builtin_amdgcn_mfma_f32_16x16x32_bf16(as_bf8(sm.xst[kt][lane]),      wiF, a0, 0, 0, 0);
      a1 = __builtin_amdgcn_mfma_f32_16x16x32_bf16(as_bf8(sm.xst[32 + kt][lane]), wiF, a1, 0, 0, 0);
    }

    // ---- C3. write first 8 h frags (masked); issue last 8 loads ----
#pragma unroll
    for (int i = 0; i < 8; ++i) {
      int g2 = wv + 4 * i;
      int msk = (g2 >> 5) ? trm1 : trm0;
      u32x4 v = hq[i];
      if (msk) v = (u32x4){0, 0, 0, 0};
      sm.hst[g2][lane] = v;
    }
#pragma unroll
    for (int i = 8; i < 16; ++i) {
      int g2 = wv + 4 * i;
      int kt = g2 & 31;
      int grow = (g2 >> 5) ? srow1 : srow0;
      hq[i - 8] = *reinterpret_cast<const u32x4*>(hslot + (size_t)grow * F_DIM + kt * 32 + fcol0);
    }

    // ---- C4. x @ Wi second half ----
#pragma unroll
    for (int kt = 16; kt < 32; ++kt) {
      bf8 wiF = wib[kt * 64];
      a0 = __builtin_amdgcn_mfma_f32_16x16x32_bf16(as_bf8(sm.xst[kt][lane]),      wiF, a0, 0, 0, 0);
      a1 = __builtin_amdgcn_mfma_f32_16x16x32_bf16(as_bf8(sm.xst[32 + kt][lane]), wiF, a1, 0, 0, 0);
    }

    // ---- C5. write last 8 h frags ----
#pragma unroll
    for (int i = 8; i < 16; ++i) {
      int g2 = wv + 4 * i;
      int msk = (g2 >> 5) ? trm1 : trm0;
      u32x4 v = hq[i - 8];
      if (msk) v = (u32x4){0, 0, 0, 0};
      sm.hst[g2][lane] = v;
    }
    __syncthreads();

    // ---- D. h @ Wh (weights in registers) ----
#pragma unroll
    for (int kt = 0; kt < 32; ++kt) {
      a0 = __builtin_amdgcn_mfma_f32_16x16x32_bf16(as_bf8(sm.hst[kt][lane]),      wh[kt], a0, 0, 0, 0);
      a1 = __builtin_amdgcn_mfma_f32_16x16x32_bf16(as_bf8(sm.hst[32 + kt][lane]), wh[kt], a1, 0, 0, 0);
    }

    // ---- E. gate exchange ----
#pragma unroll
    for (int r = 0; r < 4; ++r) {
      sm.gates[wv][0][oct * 4 + r][col] = a0[r];
      sm.gates[wv][1][oct * 4 + r][col] = a1[r];
    }
    __syncthreads();

    // ---- F. epilogue: each wave owns 8 rows (2 cells/lane) ----
    float hn_sv[2];
#pragma unroll
    for (int c2 = 0; c2 < 2; ++c2) {
      int wr = wv * 8 + c2 * 4 + oct;
      int mt = wr >> 4, rr = wr & 15;
      int bg = mpair * 32 + wr;
      int trm = term[t * B_DIM + bg];
      float vi = sm.gates[0][mt][rr][col] + b4[0];
      float vf = sm.gates[1][mt][rr][col] + b4[1];
      float vg = sm.gates[2][mt][rr][col] + b4[2];
      float vo = sm.gates[3][mt][rr][col] + b4[3];
      float cp = trm ? 0.f : c_reg[c2];
      float cn = sigm(vf) * cp + sigm(vi) * tanh_(vg);
      float hn = sigm(vo) * tanh_(cn);
      c_reg[c2] = cn;
      hn_sv[c2] = hn;
    }

    // ---- G. publish h_{t+1}: each wave stores its own 8 rows (sc1) ----
    if (t < T_DIM - 1) {
      unsigned short* hnext = ring + (size_t)(t + 1) * 131072;
#pragma unroll
      for (int c2 = 0; c2 < 2; ++c2) {
        unsigned int my = f2bf(hn_sv[c2]);
        unsigned int nb = (unsigned int)__shfl_xor((int)my, 1, 64);
        if (!(col & 1)) {
          int row = mpair * 32 + wv * 8 + c2 * 4 + oct;
          unsigned int pk = my | (nb << 16);
          st_sc1(reinterpret_cast<unsigned int*>(hnext + (size_t)row * F_DIM + (fi & ~1)), pk);
        }
      }
    }
    __syncthreads();   // drains all waves' h stores before flag publish

    if (wv == 0) {
      // ---- H. arrival: one store on own line ----
      if (lane == 0) st_sc1(flagsA + (wg << 5), (unsigned int)(t + 1));
      // ---- I0. wave0's deferred HBM stores ----
#pragma unroll
      for (int c2 = 0; c2 < 2; ++c2) {
        int wr = c2 * 4 + oct;
        int bg = mpair * 32 + wr;
        out[((size_t)t * B_DIM + bg) * F_DIM + fi] = hn_sv[c2];
        if (t == T_DIM - 1) {
          fc[(size_t)bg * F_DIM + fi] = c_reg[c2];
          fh[(size_t)bg * F_DIM + fi] = hn_sv[c2];
        }
      }
    } else {
      // ---- I. deferred HBM stores ----
#pragma unroll
      for (int c2 = 0; c2 < 2; ++c2) {
        int wr = wv * 8 + c2 * 4 + oct;
        int bg = mpair * 32 + wr;
        out[((size_t)t * B_DIM + bg) * F_DIM + fi] = hn_sv[c2];
        if (t == T_DIM - 1) {
          fc[(size_t)bg * F_DIM + fi] = c_reg[c2];
          fh[(size_t)bg * F_DIM + fi] = hn_sv[c2];
        }
      }
      // ---- J. stage x(t+1) while the grid synchronizes (waves 1-3) ----
      if (t < T_DIM - 1) {
        const float* xn = x + (size_t)(t + 1) * B_DIM * F_DIM;
#pragma unroll 2
        for (int i = 0; i < 22; ++i) {
          int s = (wv - 1) * 22 + i;
          if (s < 64) stage_slot(&sm, xn, s, lane, srow0, srow1, fcol0);
        }
      }
    }
  }
}

extern "C" void kernel_launch(void* const* d_in, const int* in_sizes, int n_in,
                              void* d_out, int out_size, void* d_ws, size_t ws_size,
                              hipStream_t stream) {
  const float* x    = (const float*)d_in[0];
  const int*   term = (const int*)d_in[1];
  const float* c0   = (const float*)d_in[2];
  const float* h0   = (const float*)d_in[3];
  const float* Wi   = (const float*)d_in[4];
  const float* Wh   = (const float*)d_in[5];
  const float* bias = (const float*)d_in[6];
  float* out = (float*)d_out;
  char*  ws  = (char*)d_ws;

  if (ws_size < WS_NEED) return;

  unsigned int*   ctrl = (unsigned int*)(ws + OFF_CTRL);
  unsigned short* wip  = (unsigned short*)(ws + OFF_WIP);
  unsigned short* whp  = (unsigned short*)(ws + OFF_WHP);
  unsigned short* ring = (unsigned short*)(ws + OFF_RING);

  hipMemsetAsync(ctrl, 0, 65536, stream);
  pack_w<<<dim3(4096), dim3(256), 0, stream>>>(Wi, Wh, wip, whp);
  pack_h<<<dim3(512),  dim3(256), 0, stream>>>(h0, ring);
  lstm_scan<<<dim3(NWGS), dim3(256), 0, stream>>>(x, wip, whp, ring, bias, term, c0, out, ctrl);
}